// Round 1
// baseline (175.713 us; speedup 1.0000x reference)
//
#include <hip/hip_runtime.h>

// YOLOv3 decode. R6: bytes-per-request attack. R5 showed read BW plateaus
// at ~1.8 TB/s regardless of wave count -> per-CU outstanding-REQUEST limit,
// not outstanding-bytes. Scalar dword loads carry 256 B/wave/request; switch
// to dwordx4 (1 KiB/wave/request, 4x bytes per queue slot). Each thread now
// owns 4 consecutive hw positions (HW=2704/676 divisible by 4; all float4
// loads 16B-aligned). Quad seg-split kept: 4 threads cover 80 classes,
// argmax is per-component reduce + quad __shfl_xor. 13x13 (HW=169, odd,
// 4.8% of data) keeps the scalar path.

#define NCLS 80

// ---------- scalar path (13x13 only) ----------
template<int HW, int W>
__device__ __forceinline__ void decode4(
    const float* __restrict__ in, const float* __restrict__ anch,
    float scale, float inv_case, float th,
    int a, int t, int row_base, int B,
    float* __restrict__ boxes, float* __restrict__ mask)
{
    if (t >= B * HW * 4) return;
    const int rt  = t >> 2;          // row-in-scale-anchor: b*HW + hw
    const int seg = t & 3;           // class segment 0..3
    const int b   = rt / HW;         // compile-time divisor -> magic mul
    const int hw  = rt - b * HW;

    const float* p = in + ((size_t)b * 255 + (size_t)a * 85) * HW + hw;

    const float* pc = p + (size_t)(5 + seg * 20) * HW;
    float v[20];
#pragma unroll
    for (int j = 0; j < 20; ++j)
        v[j] = pc[(size_t)j * HW];

    float best = v[0];
    int   bi   = seg * 20;
#pragma unroll
    for (int j = 1; j < 20; ++j)
        if (v[j] > best) { best = v[j]; bi = seg * 20 + j; }

    float o0 = p[0 * (size_t)HW];
    float o1 = p[1 * (size_t)HW];
    float o2 = p[2 * (size_t)HW];
    float o3 = p[3 * (size_t)HW];
    float o4 = p[4 * (size_t)HW];

#pragma unroll
    for (int m = 1; m <= 2; m <<= 1) {
        float ob = __shfl_xor(best, m);
        int   oi = __shfl_xor(bi,   m);
        if (ob > best || (ob == best && oi < bi)) { best = ob; bi = oi; }
    }

    if (seg == 0) {
        int h = hw / W;
        int w = hw - h * W;
        float px = 1.0f / (1.0f + __expf(-o0));
        float cx = ((float)w + o1) * scale;
        float cy = ((float)h + o2) * scale;
        float bw = anch[2 * a + 0] * __expf(o3) * inv_case;
        float bh = anch[2 * a + 1] * __expf(o4) * inv_case;

        int row = row_base + rt * 3 + a;
        float2* ob2 = reinterpret_cast<float2*>(boxes + (size_t)row * 6);
        ob2[0] = make_float2(px, cx);
        ob2[1] = make_float2(cy, bw);
        ob2[2] = make_float2(bh, (float)bi);
        mask[row] = (o0 > th) ? 1.0f : 0.0f;
    }
}

// ---------- vectorized path: 4 hw positions / thread via dwordx4 ----------
template<int HWQ, int W>   // HWQ = HW/4
__device__ __forceinline__ void decode4x4(
    const float* __restrict__ in, const float* __restrict__ anch,
    float scale, float inv_case, float th,
    int a, int t, int row_base, int B,
    float* __restrict__ boxes, float* __restrict__ mask)
{
    if (t >= B * HWQ * 4) return;
    const int rt  = t >> 2;          // b*HWQ + hwq ; quad of 4 lanes shares rt
    const int seg = t & 3;           // class segment 0..3
    const int b   = rt / HWQ;        // compile-time divisor -> magic mul
    const int hwq = rt - b * HWQ;
    constexpr int HW = HWQ * 4;

    // element offset = (b*255 + a*85 + ch)*HW + hwq*4 ; HW%4==0 -> 16B aligned
    const float* p = in + ((size_t)b * 255 + (size_t)a * 85) * HW + hwq * 4;

    // 20 class channels for this segment, one float4 (4 hw positions) each.
    // All 20 issued back-to-back: 20 KiB in flight per wave from these alone.
    const float4* pc = reinterpret_cast<const float4*>(p + (size_t)(5 + seg * 20) * HW);
    float4 v[20];
#pragma unroll
    for (int j = 0; j < 20; ++j)
        v[j] = pc[(size_t)j * HWQ];

    // box channels: all 4 segs load identical addresses (same lines -> L1
    // broadcast, no extra HBM traffic); issued before the reduce so their
    // latency hides under the compare chain + shuffles.
    const float4* pb = reinterpret_cast<const float4*>(p);
    float4 o0 = pb[0];
    float4 o1 = pb[1 * HWQ];
    float4 o2 = pb[2 * HWQ];
    float4 o3 = pb[3 * HWQ];
    float4 o4 = pb[4 * HWQ];

    // per-component running argmax (strict > keeps earliest index, matching
    // jnp.argmax first-max semantics within this segment)
    float best[4] = { v[0].x, v[0].y, v[0].z, v[0].w };
    int   bi[4]   = { seg * 20, seg * 20, seg * 20, seg * 20 };
#pragma unroll
    for (int j = 1; j < 20; ++j) {
        const float vj[4] = { v[j].x, v[j].y, v[j].z, v[j].w };
#pragma unroll
        for (int k = 0; k < 4; ++k)
            if (vj[k] > best[k]) { best[k] = vj[k]; bi[k] = seg * 20 + j; }
    }

    // quad butterfly: max with smallest-index tie-break, per component
#pragma unroll
    for (int m = 1; m <= 2; m <<= 1) {
#pragma unroll
        for (int k = 0; k < 4; ++k) {
            float ob = __shfl_xor(best[k], m);
            int   oi = __shfl_xor(bi[k],   m);
            if (ob > best[k] || (ob == best[k] && oi < bi[k])) {
                best[k] = ob; bi[k] = oi;
            }
        }
    }

    if (seg == 0) {
        const float a0 = anch[2 * a + 0];
        const float a1 = anch[2 * a + 1];
        const float e0[4] = { o0.x, o0.y, o0.z, o0.w };
        const float e1[4] = { o1.x, o1.y, o1.z, o1.w };
        const float e2[4] = { o2.x, o2.y, o2.z, o2.w };
        const float e3[4] = { o3.x, o3.y, o3.z, o3.w };
        const float e4[4] = { o4.x, o4.y, o4.z, o4.w };
#pragma unroll
        for (int k = 0; k < 4; ++k) {
            const int hw = hwq * 4 + k;      // may cross a W-row (W=26): per-k h,w
            const int h  = hw / W;           // compile-time divisor -> magic mul
            const int w  = hw - h * W;
            float px = 1.0f / (1.0f + __expf(-e0[k]));
            float cx = ((float)w + e1[k]) * scale;
            float cy = ((float)h + e2[k]) * scale;
            float bw = a0 * __expf(e3[k]) * inv_case;
            float bh = a1 * __expf(e4[k]) * inv_case;

            const int row = row_base + (b * HW + hw) * 3 + a;
            float2* ob2 = reinterpret_cast<float2*>(boxes + (size_t)row * 6);
            ob2[0] = make_float2(px, cx);
            ob2[1] = make_float2(cy, bw);
            ob2[2] = make_float2(bh, (float)bi[k]);
            mask[row] = (e0[k] > th) ? 1.0f : 0.0f;
        }
    }
}

__global__ __launch_bounds__(256) void detector_kernel(
    const float* __restrict__ in13, const float* __restrict__ in26,
    const float* __restrict__ in52,
    const float* __restrict__ a13, const float* __restrict__ a26,
    const float* __restrict__ a52,
    const float* __restrict__ thp, const int* __restrict__ casep,
    float* __restrict__ boxes, float* __restrict__ mask,
    int B, int nb52, int nb26)
{
    const int a  = blockIdx.y;
    const int bx = blockIdx.x;
    const float th       = thp[0];
    const float inv_case = 1.0f / (float)casep[0];

    if (bx < nb52) {
        int t = bx * 256 + threadIdx.x;
        decode4x4<676, 52>(in52, a52, 8.0f * inv_case, inv_case, th,
                           a, t, B * (169 + 676) * 3, B, boxes, mask);
    } else if (bx < nb52 + nb26) {
        int t = (bx - nb52) * 256 + threadIdx.x;
        decode4x4<169, 26>(in26, a26, 16.0f * inv_case, inv_case, th,
                           a, t, B * 169 * 3, B, boxes, mask);
    } else {
        int t = (bx - nb52 - nb26) * 256 + threadIdx.x;
        decode4<169, 13>(in13, a13, 32.0f * inv_case, inv_case, th,
                         a, t, 0, B, boxes, mask);
    }
}

extern "C" void kernel_launch(void* const* d_in, const int* in_sizes, int n_in,
                              void* d_out, int out_size, void* d_ws, size_t ws_size,
                              hipStream_t stream) {
    const float* in13 = (const float*)d_in[0];
    const float* in26 = (const float*)d_in[1];
    const float* in52 = (const float*)d_in[2];
    const float* a13  = (const float*)d_in[3];
    const float* a26  = (const float*)d_in[4];
    const float* a52  = (const float*)d_in[5];
    const float* thp  = (const float*)d_in[6];
    const int*   casep = (const int*)d_in[7];

    const int B = in_sizes[0] / (255 * 169);

    // vec path: B * (HW/4) * 4 segs threads per scale
    const int nb52 = (B * 676 * 4 + 255) / 256;   // 52x52, HWQ=676
    const int nb26 = (B * 169 * 4 + 255) / 256;   // 26x26, HWQ=169
    const int nb13 = (B * 169 * 4 + 255) / 256;   // 13x13 scalar path

    const int nrows = B * (169 + 676 + 2704) * 3;
    float* boxes = (float*)d_out;
    float* mask  = (float*)d_out + (size_t)nrows * 6;

    dim3 grid(nb52 + nb26 + nb13, 3);
    detector_kernel<<<grid, 256, 0, stream>>>(
        in13, in26, in52, a13, a26, a52, thp, casep,
        boxes, mask, B, nb52, nb26);
}

// Round 2
// 171.645 us; speedup vs baseline: 1.0237x; 1.0237x over previous
//
#include <hip/hip_runtime.h>

// YOLOv3 decode. R7: regime change. R5/R6 plateau at 1.5-1.8 TB/s with
// per-thread gathers: compiler caps the load window (~6 loads, VGPR=36)
// and in-order vmcnt head-of-line blocking limits per-CU lines in flight
// to ~14 (HW supports 72+, per float4-copy at 6.3 TB/s). Fix: decouple
// MLP from VGPRs via global_load_lds (dest-register-free). Each WG owns
// (b, anchor, 676-hw tile); 85 channels staged in 8 double-buffered
// phases of 11 channels (29.7 KB/phase, 59.5 KB LDS, 2 WG/CU) with
// COUNTED vmcnt (never drained mid-loop). Staging = contiguous 2.7 KB
// bursts/channel. Compute: conflict-free LDS reads, fully lane-local
// argmax (no shuffles). 13-scale uses width-4 loads (channel stride
// 676 B is not 16B-aligned).

#define PHCH 11          // channels staged per phase
#define NPH  8           // 8*11 = 88 >= 85 channels
#define TLMAX 676        // largest hw-tile in floats

typedef __attribute__((address_space(1))) const void gv_t;
typedef __attribute__((address_space(3))) void lv_t;

template<int BYTES>
__device__ __forceinline__ void gl(const float* g, float* l) {
    if constexpr (BYTES == 16)
        __builtin_amdgcn_global_load_lds((gv_t*)g, (lv_t*)l, 16, 0, 0);
    else
        __builtin_amdgcn_global_load_lds((gv_t*)g, (lv_t*)l, 4, 0, 0);
}

// channels this wave stages in phase p (wave w owns local channels 3w..3w+2)
__device__ __forceinline__ int nch_wave(int wv, int p) {
    const int nc = (p == NPH - 1) ? (85 - PHCH * (NPH - 1)) : PHCH;  // 8 or 11
    const int n  = nc - wv * 3;
    return n < 0 ? 0 : (n > 3 ? 3 : n);
}

__device__ __forceinline__ void waitcnt_vm(int n) {
    switch (n) {                       // n in {0, 6, 9} only
        case 0:  asm volatile("s_waitcnt vmcnt(0)" ::: "memory"); break;
        case 6:  asm volatile("s_waitcnt vmcnt(6)" ::: "memory"); break;
        default: asm volatile("s_waitcnt vmcnt(9)" ::: "memory"); break;
    }
}

// stage this wave's channels of phase p into buf; 3 instrs/channel:
// offsets {0, 64*VF, TL-64*VF} floats (tail backed off -> overlap re-writes
// identical bytes, never OOB, no exec masking needed). Returns instr count.
template<int HW, int TL, int VF>
__device__ __forceinline__ int stage(const float* __restrict__ base, float* buf,
                                     int wv, int lane, int p) {
    const int c0 = wv * 3;
    const int n  = nch_wave(wv, p);
    constexpr int VB = VF * 4;
    for (int i = 0; i < n; ++i) {
        const float* g = base + (size_t)(PHCH * p + c0 + i) * HW;
        float* l = buf + (c0 + i) * TL;
        gl<VB>(g + (size_t)lane * VF,                  l);
        gl<VB>(g + 64 * VF + (size_t)lane * VF,        l + 64 * VF);
        gl<VB>(g + (TL - 64 * VF) + (size_t)lane * VF, l + (TL - 64 * VF));
    }
    return 3 * n;
}

template<int HW, int W, int TILES, int VF>
__device__ __forceinline__ void decode_staged(
    const float* __restrict__ in, const float* __restrict__ anch,
    float scale, float inv_case, float th,
    int u, int B, int row_base,
    float* __restrict__ boxes, float* __restrict__ mask, float* lds)
{
    constexpr int TL = HW / TILES;           // 676 / 676 / 169
    constexpr int SLOTS = (TL + 255) / 256;  // 3 / 3 / 1

    const int tile = u % TILES;
    const int a    = (u / TILES) % 3;
    const int b    = u / (TILES * 3);
    const int tid  = threadIdx.x;
    const int wv   = tid >> 6;
    const int lane = tid & 63;

    const float* base = in + ((size_t)b * 255 + (size_t)a * 85) * HW + (size_t)tile * TL;

    // prologue: phase 0 into buffer 0
    stage<HW, TL, VF>(base, lds, wv, lane, 0);

    float best[SLOTS];
    int   bi[SLOTS];
    float bx[5][SLOTS];
#pragma unroll
    for (int s = 0; s < SLOTS; ++s) { best[s] = -1e30f; bi[s] = 0; }

    for (int p = 0; p < NPH; ++p) {
        float* buf = lds + (p & 1) * (PHCH * TL);
        int wcnt = 0;
        if (p + 1 < NPH)   // issue next phase; its buffer's readers finished at prev trailing barrier
            wcnt = stage<HW, TL, VF>(base, lds + ((p + 1) & 1) * (PHCH * TL), wv, lane, p + 1);
        waitcnt_vm(wcnt);                  // wait phase p only; p+1 stays in flight
        __builtin_amdgcn_s_barrier();
        asm volatile("" ::: "memory");

        if (p == 0) {
#pragma unroll
            for (int cl = 0; cl < PHCH; ++cl) {
#pragma unroll
                for (int s = 0; s < SLOTS; ++s) {
                    const int hw = tid + s * 256;
                    if ((s + 1) * 256 <= TL || hw < TL) {
                        const float v = buf[cl * TL + hw];
                        if (cl < 5) bx[cl][s] = v;          // static index (unrolled)
                        else if (v > best[s]) { best[s] = v; bi[s] = cl - 5; }
                    }
                }
            }
        } else {
            const int nc = (p == NPH - 1) ? (85 - PHCH * (NPH - 1)) : PHCH;
            for (int cl = 0; cl < nc; ++cl) {
#pragma unroll
                for (int s = 0; s < SLOTS; ++s) {
                    const int hw = tid + s * 256;
                    if ((s + 1) * 256 <= TL || hw < TL) {
                        const float v = buf[cl * TL + hw];
                        if (v > best[s]) { best[s] = v; bi[s] = p * PHCH + cl - 5; }
                    }
                }
            }
        }
        asm volatile("" ::: "memory");
        __builtin_amdgcn_s_barrier();      // readers done before next overwrite
    }

    const float a0 = anch[2 * a + 0], a1 = anch[2 * a + 1];
#pragma unroll
    for (int s = 0; s < SLOTS; ++s) {
        const int hwl = tid + s * 256;
        if ((s + 1) * 256 <= TL || hwl < TL) {
            const int ghw = tile * TL + hwl;
            const int hh = ghw / W;            // compile-time W -> magic mul
            const int ww = ghw - hh * W;
            const float px = 1.0f / (1.0f + __expf(-bx[0][s]));
            const float cx = ((float)ww + bx[1][s]) * scale;
            const float cy = ((float)hh + bx[2][s]) * scale;
            const float bw = a0 * __expf(bx[3][s]) * inv_case;
            const float bh = a1 * __expf(bx[4][s]) * inv_case;
            const int row = row_base + (b * HW + ghw) * 3 + a;
            float2* ob2 = reinterpret_cast<float2*>(boxes + (size_t)row * 6);
            ob2[0] = make_float2(px, cx);
            ob2[1] = make_float2(cy, bw);
            ob2[2] = make_float2(bh, (float)bi[s]);
            mask[row] = (bx[0][s] > th) ? 1.0f : 0.0f;
        }
    }
}

__global__ __launch_bounds__(256) void detector_kernel(
    const float* __restrict__ in13, const float* __restrict__ in26,
    const float* __restrict__ in52,
    const float* __restrict__ a13, const float* __restrict__ a26,
    const float* __restrict__ a52,
    const float* __restrict__ thp, const int* __restrict__ casep,
    float* __restrict__ boxes, float* __restrict__ mask, int B)
{
    __shared__ float lds[2 * PHCH * TLMAX];   // 59,488 B -> 2 WG/CU
    const int gx = blockIdx.x;
    const float th       = thp[0];
    const float inv_case = 1.0f / (float)casep[0];
    const int n52 = B * 12;                    // B*3 anchors*4 tiles (heavy first)
    const int n26 = B * 3;

    if (gx < n52)
        decode_staged<2704, 52, 4, 4>(in52, a52, 8.0f * inv_case, inv_case, th,
                                      gx, B, B * (169 + 676) * 3, boxes, mask, lds);
    else if (gx < n52 + n26)
        decode_staged<676, 26, 1, 4>(in26, a26, 16.0f * inv_case, inv_case, th,
                                     gx - n52, B, B * 169 * 3, boxes, mask, lds);
    else
        decode_staged<169, 13, 1, 1>(in13, a13, 32.0f * inv_case, inv_case, th,
                                     gx - n52 - n26, B, 0, boxes, mask, lds);
}

extern "C" void kernel_launch(void* const* d_in, const int* in_sizes, int n_in,
                              void* d_out, int out_size, void* d_ws, size_t ws_size,
                              hipStream_t stream) {
    const float* in13 = (const float*)d_in[0];
    const float* in26 = (const float*)d_in[1];
    const float* in52 = (const float*)d_in[2];
    const float* a13  = (const float*)d_in[3];
    const float* a26  = (const float*)d_in[4];
    const float* a52  = (const float*)d_in[5];
    const float* thp  = (const float*)d_in[6];
    const int*   casep = (const int*)d_in[7];

    const int B = in_sizes[0] / (255 * 169);

    const int nrows = B * (169 + 676 + 2704) * 3;
    float* boxes = (float*)d_out;
    float* mask  = (float*)d_out + (size_t)nrows * 6;

    dim3 grid(B * 18);   // B*12 (52) + B*3 (26) + B*3 (13)
    detector_kernel<<<grid, 256, 0, stream>>>(
        in13, in26, in52, a13, a26, a52, thp, casep, boxes, mask, B);
}